// Round 1
// baseline (1190.812 us; speedup 1.0000x reference)
//
#include <hip/hip_runtime.h>

typedef _Float16 half8_t __attribute__((ext_vector_type(8)));
typedef _Float16 half2_t __attribute__((ext_vector_type(2)));
typedef float floatx4 __attribute__((ext_vector_type(4)));

#define B_DIM 256
#define T_DIM 512
#define E_DIM 256
#define H_DIM 256
#define MROWS (B_DIM * T_DIM)  // 131072 rows of [B*T, E]

__device__ __forceinline__ half2_t mk2(_Float16 x, _Float16 y) {
    half2_t v; v[0] = x; v[1] = y; return v;
}

__device__ __forceinline__ float fdot2f(half2_t a, half2_t b, float c) {
#if __has_builtin(__builtin_amdgcn_fdot2)
    return __builtin_amdgcn_fdot2(a, b, c, false);
#else
    return c + (float)a[0] * (float)b[0] + (float)a[1] * (float)b[1];
#endif
}

// ---------------------------------------------------------------------------
// Phase 1: X[m][n] = emb[m][:E] . Wg[n][:E] + bg[n]  for gates g in {z,r,m}
//   gate 0 -> Xz (f16, ws), gate 1 -> Xr (f16, ws), gate 2 -> Xm (f32, d_out)
// f16 MFMA 16x16x32, 128x128 tiles, BK=32, fp32->f16 convert fused in staging.
// ---------------------------------------------------------------------------
__global__ __launch_bounds__(256, 2) void gemm_x(
    const float* __restrict__ emb,
    const float* __restrict__ Wz, const float* __restrict__ bz,
    const float* __restrict__ Wr, const float* __restrict__ br,
    const float* __restrict__ Wm, const float* __restrict__ bm,
    _Float16* __restrict__ Xz, _Float16* __restrict__ Xr,
    float* __restrict__ Xm)
{
    const int n0 = blockIdx.x * 128;        // 0..640 (6 n-tiles over 3 gates)
    const int m0 = blockIdx.y * 128;
    const int gate = n0 >> 8;               // 128-tile pairs per gate
    const int ng0 = n0 & 255;
    const float* W    = (gate == 0) ? Wz : (gate == 1) ? Wr : Wm;
    const float* bias = (gate == 0) ? bz : (gate == 1) ? br : bm;

    // padded row stride 40 halves (80 B): 16B-aligned rows, <=2-way bank alias
    __shared__ __align__(16) _Float16 lA[128 * 40];
    __shared__ __align__(16) _Float16 lB[128 * 40];

    const int t = threadIdx.x;
    const int lane = t & 63;
    const int wave = t >> 6;
    const int wm = (wave >> 1) * 64;
    const int wn = (wave & 1) * 64;
    const int lq = lane >> 4;               // quad
    const int lr = lane & 15;

    floatx4 acc[4][4];
    #pragma unroll
    for (int i = 0; i < 4; ++i)
        #pragma unroll
        for (int j = 0; j < 4; ++j)
            acc[i][j] = (floatx4)0.0f;

    const int srow = t >> 1;                // 0..127
    const int scol = (t & 1) * 16;          // 0 or 16 (halves within 32-k tile)
    const float* aSrc = emb + (size_t)(m0 + srow) * E_DIM + scol;
    const float* bSrc = W + (size_t)(ng0 + srow) * (E_DIM + H_DIM) + scol;

    for (int k0 = 0; k0 < E_DIM; k0 += 32) {
        float ta[16], tb[16];
        #pragma unroll
        for (int u = 0; u < 4; ++u) {
            *(float4*)(ta + 4 * u) = *(const float4*)(aSrc + k0 + 4 * u);
            *(float4*)(tb + 4 * u) = *(const float4*)(bSrc + k0 + 4 * u);
        }
        half8_t a0, a1, b0, b1;
        #pragma unroll
        for (int u = 0; u < 8; ++u) {
            a0[u] = (_Float16)ta[u]; a1[u] = (_Float16)ta[u + 8];
            b0[u] = (_Float16)tb[u]; b1[u] = (_Float16)tb[u + 8];
        }
        __syncthreads();   // previous iter's LDS reads done
        *(half8_t*)&lA[srow * 40 + scol]     = a0;
        *(half8_t*)&lA[srow * 40 + scol + 8] = a1;
        *(half8_t*)&lB[srow * 40 + scol]     = b0;
        *(half8_t*)&lB[srow * 40 + scol + 8] = b1;
        __syncthreads();

        half8_t af[4], bf[4];
        #pragma unroll
        for (int i = 0; i < 4; ++i)
            af[i] = *(const half8_t*)&lA[(wm + i * 16 + lr) * 40 + lq * 8];
        #pragma unroll
        for (int j = 0; j < 4; ++j)
            bf[j] = *(const half8_t*)&lB[(wn + j * 16 + lr) * 40 + lq * 8];
        #pragma unroll
        for (int i = 0; i < 4; ++i)
            #pragma unroll
            for (int j = 0; j < 4; ++j)
                acc[i][j] = __builtin_amdgcn_mfma_f32_16x16x32_f16(
                    af[i], bf[j], acc[i][j], 0, 0, 0);
    }

    // epilogue: D[row=(lane>>4)*4+r][col=lane&15], add bias, store per gate
    if (gate < 2) {
        _Float16* dst = (gate == 0) ? Xz : Xr;
        #pragma unroll
        for (int j = 0; j < 4; ++j) {
            const int ng = ng0 + wn + j * 16 + lr;
            const float bv = bias[ng];
            #pragma unroll
            for (int i = 0; i < 4; ++i) {
                const int mrow = m0 + wm + i * 16 + lq * 4;
                #pragma unroll
                for (int r = 0; r < 4; ++r)
                    dst[(size_t)(mrow + r) * H_DIM + ng] =
                        (_Float16)(acc[i][j][r] + bv);
            }
        }
    } else {
        #pragma unroll
        for (int j = 0; j < 4; ++j) {
            const int ng = ng0 + wn + j * 16 + lr;
            const float bv = bias[ng];
            #pragma unroll
            for (int i = 0; i < 4; ++i) {
                const int mrow = m0 + wm + i * 16 + lq * 4;
                #pragma unroll
                for (int r = 0; r < 4; ++r)
                    Xm[(size_t)(mrow + r) * H_DIM + ng] = acc[i][j][r] + bv;
            }
        }
    }
}

// ---------------------------------------------------------------------------
// Phase 2: persistent recurrence. One WG per batch element (256 WGs = 256 CUs).
// Recurrent weights (h-halves of Wz/Wr/Wm) held as f16 in VGPRs:
//   threads 0..255: z-gate row jA; threads 256..511: r-gate row jA  (128 VGPRs)
//   thread pair (2j, 2j+1): m-gate row j split in two k-halves      (64 VGPRs)
// Per step: phase A (z,r dots) -> barrier -> phase B (m dot, pair-reduced via
// shfl_xor) -> h update -> barrier. X contributions prefetched one step ahead.
// ---------------------------------------------------------------------------
__global__ __launch_bounds__(512, 2) void gru_rec(
    const float* __restrict__ Wz,
    const float* __restrict__ Wr,
    const float* __restrict__ Wm,
    const _Float16* __restrict__ Xz,
    const _Float16* __restrict__ Xr,
    float* __restrict__ out)   // holds Xm on entry per row; overwritten with h
{
    const int b = blockIdx.x;
    const int t = threadIdx.x;
    const int jA = t & 255;
    const int jB = t >> 1;
    const int hB = t & 1;

    __shared__ __align__(16) _Float16 hh[256];  // h as f16 (for dots)
    __shared__ float hf[256];                    // h master fp32
    __shared__ __align__(16) _Float16 rh[256];  // r*h as f16
    __shared__ float zl[256];                    // z gate values

    // ---- load recurrent weights into registers (fp32 -> f16) ----
    half2_t w1[128];
    {
        const float* wrow = ((t < 256) ? Wz : Wr) + (size_t)jA * 512 + 256;
        #pragma unroll
        for (int k = 0; k < 64; ++k) {
            float4 f = ((const float4*)wrow)[k];
            w1[2 * k]     = mk2((_Float16)f.x, (_Float16)f.y);
            w1[2 * k + 1] = mk2((_Float16)f.z, (_Float16)f.w);
        }
    }
    half2_t w2[64];
    {
        const float* wrow = Wm + (size_t)jB * 512 + 256 + hB * 128;
        #pragma unroll
        for (int k = 0; k < 32; ++k) {
            float4 f = ((const float4*)wrow)[k];
            w2[2 * k]     = mk2((_Float16)f.x, (_Float16)f.y);
            w2[2 * k + 1] = mk2((_Float16)f.z, (_Float16)f.w);
        }
    }

    if (t < 256) { hh[t] = (_Float16)0.0f; hf[t] = 0.0f; }
    __syncthreads();

    const size_t rowbase = (size_t)b * T_DIM * H_DIM;
    // prefetch step-0 inputs
    float xa_n = (t < 256) ? (float)Xz[rowbase + jA] : (float)Xr[rowbase + jA];
    float xm_n = (hB == 0) ? out[rowbase + jB] : 0.0f;

    for (int ts = 0; ts < T_DIM; ++ts) {
        const float xa = xa_n;
        const float xm = xm_n;
        if (ts + 1 < T_DIM) {   // prefetch next step (hidden behind the dots)
            const size_t nb = rowbase + (size_t)(ts + 1) * H_DIM;
            xa_n = (t < 256) ? (float)Xz[nb + jA] : (float)Xr[nb + jA];
            xm_n = (hB == 0) ? out[nb + jB] : 0.0f;
        }

        // ---- phase A: a = xa + Wh[jA] . h  (z for t<256, r for t>=256) ----
        float a0 = xa, a1 = 0.f, a2 = 0.f, a3 = 0.f;
        const half8_t* hp8 = (const half8_t*)hh;
        #pragma unroll
        for (int k = 0; k < 32; ++k) {
            half8_t hv = hp8[k];
            a0 = fdot2f(w1[4 * k],     mk2(hv[0], hv[1]), a0);
            a1 = fdot2f(w1[4 * k + 1], mk2(hv[2], hv[3]), a1);
            a2 = fdot2f(w1[4 * k + 2], mk2(hv[4], hv[5]), a2);
            a3 = fdot2f(w1[4 * k + 3], mk2(hv[6], hv[7]), a3);
        }
        const float a = (a0 + a1) + (a2 + a3);
        const float g = 1.0f / (1.0f + __expf(-a));   // sigmoid
        if (t < 256) zl[jA] = g;                       // z
        else         rh[jA] = (_Float16)(g * hf[jA]);  // r*h
        __syncthreads();

        // ---- phase B: half-dot Wm_h[jB] . (r*h), pair-reduce via shuffle ----
        float c0 = 0.f, c1 = 0.f;
        const half8_t* rp8 = (const half8_t*)(rh + hB * 128);
        #pragma unroll
        for (int k = 0; k < 16; ++k) {
            half8_t rv = rp8[k];
            c0 = fdot2f(w2[4 * k],     mk2(rv[0], rv[1]), c0);
            c1 = fdot2f(w2[4 * k + 1], mk2(rv[2], rv[3]), c1);
            c0 = fdot2f(w2[4 * k + 2], mk2(rv[4], rv[5]), c0);
            c1 = fdot2f(w2[4 * k + 3], mk2(rv[6], rv[7]), c1);
        }
        float c = c0 + c1;
        c += __shfl_xor(c, 1);
        if (hB == 0) {
            const float am = c + xm;                            // + Xm + bm
            const float hcand = 2.0f / (1.0f + __expf(-2.0f * am)) - 1.0f;
            const float z = zl[jB];
            const float hn = (1.0f - z) * hf[jB] + z * hcand;
            out[rowbase + (size_t)ts * H_DIM + jB] = hn;
            hf[jB] = hn;
            hh[jB] = (_Float16)hn;
        }
        __syncthreads();
    }
}

extern "C" void kernel_launch(void* const* d_in, const int* in_sizes, int n_in,
                              void* d_out, int out_size, void* d_ws, size_t ws_size,
                              hipStream_t stream) {
    (void)in_sizes; (void)n_in; (void)out_size; (void)ws_size;
    const float* emb = (const float*)d_in[0];
    const float* Wz  = (const float*)d_in[1];
    const float* bz  = (const float*)d_in[2];
    const float* Wr  = (const float*)d_in[3];
    const float* br  = (const float*)d_in[4];
    const float* Wm  = (const float*)d_in[5];
    const float* bm  = (const float*)d_in[6];
    float* out = (float*)d_out;

    _Float16* Xz = (_Float16*)d_ws;                      // [131072][256] f16
    _Float16* Xr = Xz + (size_t)MROWS * H_DIM;           // [131072][256] f16

    dim3 g1(6, MROWS / 128);
    gemm_x<<<g1, 256, 0, stream>>>(emb, Wz, bz, Wr, br, Wm, bm, Xz, Xr, out);
    gru_rec<<<B_DIM, 512, 0, stream>>>(Wz, Wr, Wm, Xz, Xr, out);
}